// Round 7
// baseline (5114.084 us; speedup 1.0000x reference)
//
#include <hip/hip_runtime.h>
#include <stdint.h>

typedef unsigned short ushort_t;
using bfx8 = __attribute__((ext_vector_type(8))) short;
using f32x4 = __attribute__((ext_vector_type(4))) float;

#define DEVINL static __device__ __forceinline__

DEVINL float bits2f(unsigned int b) { union { unsigned int i; float f; } v; v.i = b; return v.f; }
DEVINL float bf2f(ushort_t u) { return bits2f(((unsigned int)u) << 16); }
DEVINL ushort_t f2bf(float x) {
  union { float f; unsigned int i; } v; v.f = x;
  return (ushort_t)((v.i + 0x7FFFu + ((v.i >> 16) & 1u)) >> 16);
}
DEVINL unsigned int mulbf2(unsigned int a, unsigned int r) {
  float a0 = bits2f(a << 16), a1 = bits2f(a & 0xFFFF0000u);
  float r0 = bits2f(r << 16), r1 = bits2f(r & 0xFFFF0000u);
  return (unsigned int)f2bf(a0 * r0) | ((unsigned int)f2bf(a1 * r1) << 16);
}

constexpr int NB2 = 2;
constexpr int HH = 48, WW = 64, HW = 3072;
constexpr int NP = NB2 * HW;
constexpr int ITERS = 12;
constexpr int CCP = 72;  // 64 channels + 8 pad

// ---------------------------------------------------------------------------
// dtype detect + weight conversion
// ---------------------------------------------------------------------------
__global__ __launch_bounds__(256) void detect_k(const ushort_t* __restrict__ src,
                                                int* __restrict__ flag) {
  const int t = threadIdx.x;
  int bad = 0;
  for (int i = t; i < 4096; i += 256) {
    const float v = bf2f(src[i]);
    if (!(fabsf(v) < 1e30f)) bad = 1;
  }
  __shared__ int s;
  if (t == 0) s = 0;
  __syncthreads();
  if (bad) atomicOr(&s, 1);
  __syncthreads();
  if (t == 0) *flag = s;
}

struct CvtArgs {
  const void* src[30];
  float* dst[30];
  int n[30];
};
__global__ __launch_bounds__(256) void cvt_all_k(CvtArgs a, const int* __restrict__ flag) {
  const bool isf32 = (*flag != 0);
  const int stride = gridDim.x * 256;
  const int t0 = blockIdx.x * 256 + threadIdx.x;
  for (int s = 0; s < 30; ++s) {
    float* dst = a.dst[s];
    const int n = a.n[s];
    if (isf32) {
      const float* src = (const float*)a.src[s];
      for (int i = t0; i < n; i += stride) dst[i] = src[i];
    } else {
      const ushort_t* src = (const ushort_t*)a.src[s];
      for (int i = t0; i < n; i += stride) dst[i] = bf2f(src[i]);
    }
  }
}

// transpose fmap (2,256,48,64) -> NHWC bf16 (NB2*HW, 256); grid y = tensor
__global__ __launch_bounds__(256) void trans_k(const void* s0, const void* s1,
                                               const void* s2, const void* s3,
                                               ushort_t* d0, ushort_t* d1,
                                               ushort_t* d2, ushort_t* d3,
                                               const int* __restrict__ flag) {
  const bool isf32 = (*flag != 0);
  int idx = blockIdx.x * 256 + threadIdx.x;
  if (idx >= NP * 256) return;
  const int t = blockIdx.y;
  const int c = idx & 255;
  const int p = idx >> 8;
  const int nb = (p >= HW) ? 1 : 0;
  const int pp = p - nb * HW;
  const void* s = (t == 0) ? s0 : (t == 1) ? s1 : (t == 2) ? s2 : s3;
  ushort_t* d = (t == 0) ? d0 : (t == 1) ? d1 : (t == 2) ? d2 : d3;
  const size_t si = ((size_t)(nb * 256 + c)) * HW + pp;
  d[idx] = isf32 ? f2bf(((const float*)s)[si]) : ((const ushort_t*)s)[si];
}

// init hidden/context for both branches; grid y = branch
__global__ __launch_bounds__(256) void init2_k(const void* cnet, const void* enet,
                                               ushort_t* net0, ushort_t* net1,
                                               ushort_t* X0, ushort_t* X1v,
                                               const int* __restrict__ flag) {
  const bool isf32 = (*flag != 0);
  int idx = blockIdx.x * 256 + threadIdx.x;
  if (idx >= NB2 * 128 * HW) return;
  const int br = blockIdx.y;
  const void* s = br ? enet : cnet;
  ushort_t* N = br ? net1 : net0;
  ushort_t* X = br ? X1v : X0;
  int nb = idx / (128 * HW);
  int r = idx - nb * 128 * HW;
  int c = r / HW;
  int p = r - c * HW;
  const size_t i0 = ((size_t)(nb * 256 + c)) * HW + p;
  const size_t i1 = ((size_t)(nb * 256 + 128 + c)) * HW + p;
  float vn = isf32 ? ((const float*)s)[i0] : bf2f(((const ushort_t*)s)[i0]);
  float vi = isf32 ? ((const float*)s)[i1] : bf2f(((const ushort_t*)s)[i1]);
  N[((size_t)nb * HW + p) * 128 + c] = f2bf(tanhf(vn));
  X[((size_t)nb * HW + p) * 256 + c] = f2bf(fmaxf(vi, 0.f));
}

// ---------------------------------------------------------------------------
// weight pack: f32 (CO, CI, KH, KW) -> B-fragment order bf16
// ---------------------------------------------------------------------------
__global__ __launch_bounds__(256) void pack_k(const float* __restrict__ src,
                                              ushort_t* __restrict__ dst,
                                              int CO, int CI_real, int KHKW,
                                              int NCHUNK, int total) {
  int idx = blockIdx.x * 256 + threadIdx.x;
  if (idx >= total) return;
  const int KST = NCHUNK * KHKW * 2;
  const int j = idx & 7;
  const int l = (idx >> 3) & 63;
  const int s = (idx >> 9) % KST;
  const int b = idx / (512 * KST);
  const int chunk = s / (KHKW * 2);
  const int r = s - chunk * KHKW * 2;
  const int t = r >> 1;
  const int half = r & 1;
  const int ci = chunk * 64 + half * 32 + ((l >> 4) & 3) * 8 + j;
  const int n = b * 16 + (l & 15);
  float v = 0.f;
  if (n < CO && ci < CI_real) v = src[((size_t)n * CI_real + ci) * KHKW + t];
  dst[idx] = f2bf(v);
}

// ---------------------------------------------------------------------------
// correlation GEMM, bf16 MFMA. grid (96, 24, 4): z = pyr*2 + nb.
// ---------------------------------------------------------------------------
struct CorrPtrs { const ushort_t* f[4]; ushort_t* out[2]; };
__global__ __launch_bounds__(256) void corr_mfma_k(CorrPtrs C) {
  const int z = blockIdx.z;
  const int pyr = z >> 1, nb = z & 1;
  const ushort_t* f1 = C.f[pyr * 2] + (size_t)nb * HW * 256;
  const ushort_t* f2 = C.f[pyr * 2 + 1] + (size_t)nb * HW * 256;
  ushort_t* out = C.out[pyr] + (size_t)nb * HW * HW;
  const int tid = threadIdx.x;
  const int l = tid & 63;
  const int wave = tid >> 6;
  const int msub = wave & 1, nsub = wave >> 1;
  const int m0 = blockIdx.x * 32, n0 = blockIdx.y * 128;
  const int q = (l >> 4) & 3, m = l & 15;
  __shared__ ushort_t als[32 * CCP];
  __shared__ ushort_t bls[128 * CCP];
  f32x4 acc0 = {0.f, 0.f, 0.f, 0.f}, acc1 = acc0, acc2 = acc0, acc3 = acc0;
  for (int c64 = 0; c64 < 4; ++c64) {
    __syncthreads();
    {
      const int cc8 = tid & 7, pixel = tid >> 3;
      *(uint4*)&als[pixel * CCP + cc8 * 8] =
          *(const uint4*)(f1 + ((size_t)(m0 + pixel)) * 256 + c64 * 64 + cc8 * 8);
    }
#pragma unroll
    for (int r = 0; r < 4; ++r) {
      const int u = tid + r * 256;
      const int cc8 = u & 7, pixel = u >> 3;
      *(uint4*)&bls[pixel * CCP + cc8 * 8] =
          *(const uint4*)(f2 + ((size_t)(n0 + pixel)) * 256 + c64 * 64 + cc8 * 8);
    }
    __syncthreads();
#pragma unroll
    for (int half = 0; half < 2; ++half) {
      const bfx8 a = *(const bfx8*)&als[(msub * 16 + m) * CCP + half * 32 + q * 8];
      const bfx8 b0 = *(const bfx8*)&bls[(nsub * 64 + 0 + m) * CCP + half * 32 + q * 8];
      const bfx8 b1 = *(const bfx8*)&bls[(nsub * 64 + 16 + m) * CCP + half * 32 + q * 8];
      const bfx8 b2 = *(const bfx8*)&bls[(nsub * 64 + 32 + m) * CCP + half * 32 + q * 8];
      const bfx8 b3 = *(const bfx8*)&bls[(nsub * 64 + 48 + m) * CCP + half * 32 + q * 8];
      acc0 = __builtin_amdgcn_mfma_f32_16x16x32_bf16(a, b0, acc0, 0, 0, 0);
      acc1 = __builtin_amdgcn_mfma_f32_16x16x32_bf16(a, b1, acc1, 0, 0, 0);
      acc2 = __builtin_amdgcn_mfma_f32_16x16x32_bf16(a, b2, acc2, 0, 0, 0);
      acc3 = __builtin_amdgcn_mfma_f32_16x16x32_bf16(a, b3, acc3, 0, 0, 0);
    }
  }
  const f32x4 accs[4] = {acc0, acc1, acc2, acc3};
#pragma unroll
  for (int f = 0; f < 4; ++f) {
#pragma unroll
    for (int reg = 0; reg < 4; ++reg) {
      const int mi = m0 + msub * 16 + q * 4 + reg;
      const int nj = n0 + nsub * 64 + f * 16 + m;
      out[(size_t)mi * HW + nj] = f2bf(accs[f][reg] * 0.0625f);
    }
  }
}

// 2x2 avg-pool, both pyramids per launch (grid y)
__global__ __launch_bounds__(256) void avgpool_k(const ushort_t* __restrict__ inA,
                                                 const ushort_t* __restrict__ inB,
                                                 ushort_t* __restrict__ outA,
                                                 ushort_t* __restrict__ outB,
                                                 int wi, int ho, int wo, int total) {
  int idx = blockIdx.x * 256 + threadIdx.x;
  if (idx >= total) return;
  const ushort_t* in = blockIdx.y ? inB : inA;
  ushort_t* out = blockIdx.y ? outB : outA;
  int pw = ho * wo;
  int p = idx / pw;
  int r = idx - p * pw;
  int y = r / wo;
  int x = r - y * wo;
  const ushort_t* src = in + (size_t)p * (4 * pw) + (2 * y) * wi + 2 * x;
  float v = (bf2f(src[0]) + bf2f(src[1]) + bf2f(src[wi]) + bf2f(src[wi + 1])) * 0.25f;
  out[idx] = f2bf(v);
}

// ---------------------------------------------------------------------------
// correlation lookup, both branches per launch (grid y = branch)
// ---------------------------------------------------------------------------
struct LkPtrs {
  const ushort_t* a0; const ushort_t* a1; const ushort_t* a2; const ushort_t* a3;
  const ushort_t* b0; const ushort_t* b1; const ushort_t* b2; const ushort_t* b3;
  const float* flow[2];
  ushort_t* out[2];
};
__global__ __launch_bounds__(384) void lookup_k(LkPtrs P) {
  const int c = threadIdx.x;
  const int p = blockIdx.x;
  const int br = blockIdx.y;
  if (c >= 324) return;
  const int nb = p / HW;
  const int rem = p - nb * HW;
  const int yy = rem >> 6, xx = rem & 63;
  const float* flow = P.flow[br];
  const float fx = flow[((size_t)(nb * 2 + 0)) * HW + rem];
  const float fy = flow[((size_t)(nb * 2 + 1)) * HW + rem];
  const int l = c / 81;
  const int k = c - l * 81;
  const float dx = (float)(k / 9) - 4.f;
  const float dy = (float)(k - (k / 9) * 9) - 4.f;
  const int hl = HH >> l, wl = WW >> l;
  const ushort_t* base =
      br ? ((l == 0) ? P.b0 : (l == 1) ? P.b1 : (l == 2) ? P.b2 : P.b3)
         : ((l == 0) ? P.a0 : (l == 1) ? P.a1 : (l == 2) ? P.a2 : P.a3);
  const ushort_t* img = base + (size_t)p * (hl * wl);
  const float s = 1.f / (float)(1 << l);
  const float xl = ((float)xx + fx) * s + dx;
  const float yl = ((float)yy + fy) * s + dy;
  const float x0f = floorf(xl), y0f = floorf(yl);
  float acc = 0.f;
#pragma unroll
  for (int dy2 = 0; dy2 < 2; ++dy2) {
#pragma unroll
    for (int dx2 = 0; dx2 < 2; ++dx2) {
      const float xi = x0f + dx2, yi = y0f + dy2;
      if (xi >= 0.f && xi <= (float)(wl - 1) && yi >= 0.f && yi <= (float)(hl - 1)) {
        const float wv = (1.f - fabsf(xl - xi)) * (1.f - fabsf(yl - yi));
        acc += wv * bf2f(img[(int)yi * wl + (int)xi]);
      }
    }
  }
  P.out[br][(size_t)p * 384 + c] = f2bf(acc);
}

// ---------------------------------------------------------------------------
// MFMA implicit-GEMM conv v2: M-tile = 64 (one image row), branch-merged.
// grid (48, COpad/(32*NF), nbr*2). NF = B-fragments per wave:
//   NF=4: N-tile 128, waves msub=w>>1 (2 A-frags each), nsub=w&1
//   NF=2: N-tile 64,  same wave layout
//   NF=1: N-tile 16,  waves msub=w (1 A-frag each), nsub=0
// ---------------------------------------------------------------------------
struct BrPtrs {
  const ushort_t* xa[2]; const ushort_t* xb[2];
  const ushort_t* zr[2]; const ushort_t* old_[2];
  void* y[2];
};
template <int KH, int KW, int PH, int PW, int ACT, int MODE, bool UPD, bool FOUT, int NF>
__global__ __launch_bounds__(256) void conv_mfma_k(
    BrPtrs P, const ushort_t* __restrict__ PB, const float* __restrict__ bias,
    int NCHUNK, int CIT_A, int ci_base, int co_base, int CO_TOT, int co_limit,
    float scale, int nbr, int ylim1) {
  constexpr int COLS = 64 + 2 * PW;
  constexpr int KHKW = KH * KW;
  constexpr int MF = (NF == 1) ? 1 : 2;
  __shared__ ushort_t als[KH * COLS * CCP];
  const int z = blockIdx.z;
  const int br = (nbr == 2) ? (z >> 1) : 0;
  const int nb = (nbr == 2) ? (z & 1) : z;
  if (br == 1 && (int)blockIdx.y >= ylim1) return;
  const ushort_t* xa = P.xa[br];
  const ushort_t* xb = P.xb[br];
  const ushort_t* zr = P.zr[br];
  const ushort_t* old_ = P.old_[br];
  void* yv = P.y[br];

  const int tid = threadIdx.x;
  const int l = tid & 63;
  const int wave = tid >> 6;
  const int msub = (NF == 1) ? wave : (wave >> 1);
  const int nsub = (NF == 1) ? 0 : (wave & 1);
  const int y0 = blockIdx.x;  // image row
  const int nbase = blockIdx.y * (2 * NF) + nsub * NF;
  const int KST = NCHUNK * KHKW * 2;
  const int q = (l >> 4) & 3;
  const int m = l & 15;
  const int xbase = msub * (MF * 16);

  f32x4 acc[MF][NF];
#pragma unroll
  for (int mf = 0; mf < MF; ++mf)
#pragma unroll
    for (int f = 0; f < NF; ++f) acc[mf][f] = {0.f, 0.f, 0.f, 0.f};
  const ushort_t* pb[NF];
#pragma unroll
  for (int f = 0; f < NF; ++f)
    pb[f] = PB + ((size_t)(nbase + f) * KST * 64 + l) * 8;
  int alane[MF];
#pragma unroll
  for (int mf = 0; mf < MF; ++mf)
    alane[mf] = (xbase + mf * 16 + m) * CCP + q * 8;

  for (int c64 = 0; c64 < NCHUNK; ++c64) {
    __syncthreads();
    constexpr int TOTU = KH * COLS * 8;
    for (int u = tid; u < TOTU; u += 256) {
      const int cc8 = u & 7;
      const int colr = u >> 3;
      const int col = colr % COLS;
      const int row = colr / COLS;
      const int gy = y0 + row - PH;
      const int gx = col - PW;
      uint4 v = {0u, 0u, 0u, 0u};
      if ((unsigned)gy < 48u && (unsigned)gx < 64u) {
        const size_t pix = (size_t)nb * HW + gy * 64 + gx;
        const int gc = c64 * 64 + cc8 * 8;
        if (MODE == 0) {
          v = *(const uint4*)(xa + pix * CIT_A + ci_base + gc);
        } else if (gc < 128) {
          v = *(const uint4*)(xa + pix * 128 + gc);
          if (MODE == 2) {
            const uint4 r = *(const uint4*)(zr + pix * 256 + 128 + gc);
            v.x = mulbf2(v.x, r.x); v.y = mulbf2(v.y, r.y);
            v.z = mulbf2(v.z, r.z); v.w = mulbf2(v.w, r.w);
          }
        } else {
          v = *(const uint4*)(xb + pix * 256 + (gc - 128));
        }
      }
      *(uint4*)&als[(row * COLS + col) * CCP + cc8 * 8] = v;
    }
    __syncthreads();
    const int sbase = c64 * KHKW * 2;
#pragma unroll
    for (int kh = 0; kh < KH; ++kh) {
#pragma unroll
      for (int kw = 0; kw < KW; ++kw) {
#pragma unroll
        for (int half = 0; half < 2; ++half) {
          const int s = sbase + (kh * KW + kw) * 2 + half;
          bfx8 a[MF];
#pragma unroll
          for (int mf = 0; mf < MF; ++mf)
            a[mf] = *(const bfx8*)&als[kh * (COLS * CCP) + kw * CCP + half * 32 + alane[mf]];
          bfx8 b[NF];
#pragma unroll
          for (int f = 0; f < NF; ++f) b[f] = *(const bfx8*)(pb[f] + (size_t)s * 512);
#pragma unroll
          for (int mf = 0; mf < MF; ++mf)
#pragma unroll
            for (int f = 0; f < NF; ++f)
              acc[mf][f] = __builtin_amdgcn_mfma_f32_16x16x32_bf16(a[mf], b[f], acc[mf][f], 0, 0, 0);
        }
      }
    }
  }
#pragma unroll
  for (int mf = 0; mf < MF; ++mf) {
#pragma unroll
    for (int f = 0; f < NF; ++f) {
      const int co = (nbase + f) * 16 + m;
      const float bv = bias[co];
#pragma unroll
      for (int reg = 0; reg < 4; ++reg) {
        const int x = xbase + mf * 16 + q * 4 + reg;
        const int p = y0 * 64 + x;
        float v = acc[mf][f][reg] + bv;
        if (ACT == 1) v = fmaxf(v, 0.f);
        if (ACT == 2) v = 1.f / (1.f + __expf(-v));
        if (ACT == 3) v = tanhf(v);
        v *= scale;
        const size_t pix = (size_t)nb * HW + p;
        if (UPD) {
          const float zv = bf2f(zr[pix * 256 + co]);
          const float old = bf2f(old_[pix * 128 + co]);
          v = (1.f - zv) * old + zv * v;
        }
        if (co_base + co < co_limit) {
          if (FOUT)
            ((float*)yv)[((size_t)nb * CO_TOT + co_base + co) * HW + p] = v;
          else
            ((ushort_t*)yv)[pix * CO_TOT + co_base + co] = f2bf(v);
        }
      }
    }
  }
}

// ---------------------------------------------------------------------------
// mf1: 7x7 conv 2->128 + flow2x fused, branch-merged. grid (48, 4).
// ---------------------------------------------------------------------------
__global__ __launch_bounds__(256) void mf1_k(const float* __restrict__ fl0,
                                             const float* __restrict__ fl1,
                                             const float* __restrict__ w,
                                             const float* __restrict__ bias,
                                             ushort_t* __restrict__ flo0,
                                             ushort_t* __restrict__ flo1,
                                             ushort_t* __restrict__ X0,
                                             ushort_t* __restrict__ X1v) {
  __shared__ float wl[12544];
  const int tid = threadIdx.x;
  for (int e = tid; e < 12544; e += 256) {
    const int co = e & 127;
    const int rest = e >> 7;
    const int ci = rest / 49;
    const int t = rest - ci * 49;
    wl[e] = w[((size_t)co * 2 + ci) * 49 + t];
  }
  __syncthreads();
  const int zz = blockIdx.y;
  const int br = zz >> 1, nb = zz & 1;
  const float* flow = br ? fl1 : fl0;
  ushort_t* flo = br ? flo1 : flo0;
  ushort_t* X = br ? X1v : X0;
  const int p = blockIdx.x * 64 + (tid & 63);
  const int cg = (tid >> 6) * 32;
  const int y = p >> 6, x = p & 63;
  float acc[32];
#pragma unroll
  for (int c = 0; c < 32; ++c) acc[c] = bias[cg + c];
  for (int ci = 0; ci < 2; ++ci) {
    const float* fp = flow + (size_t)(nb * 2 + ci) * HW;
    for (int t = 0; t < 49; ++t) {
      const int gy = y + t / 7 - 3;
      const int gx = x + t % 7 - 3;
      float f = 0.f;
      if ((unsigned)gy < 48u && (unsigned)gx < 64u) f = fp[gy * 64 + gx];
      const float* wp = &wl[(ci * 49 + t) * 128 + cg];
#pragma unroll
      for (int c = 0; c < 32; ++c) acc[c] = fmaf(f, wp[c], acc[c]);
    }
  }
  ushort_t* op = flo + ((size_t)nb * HW + p) * 128 + cg;
#pragma unroll
  for (int c = 0; c < 32; ++c) op[c] = f2bf(fmaxf(acc[c], 0.f));
  if (tid < 64) {  // fused flow2x: X[254:256] = flow
    const float vx = flow[(size_t)(nb * 2 + 0) * HW + p];
    const float vy = flow[(size_t)(nb * 2 + 1) * HW + p];
    X[((size_t)nb * HW + p) * 256 + 254] = f2bf(vx);
    X[((size_t)nb * HW + p) * 256 + 255] = f2bf(vy);
  }
}

// ---------------------------------------------------------------------------
// small kernels
// ---------------------------------------------------------------------------
__global__ __launch_bounds__(256) void flow_update_k(float* __restrict__ flow,
                                                     float* __restrict__ eflow,
                                                     const float* __restrict__ df,
                                                     const float* __restrict__ edf) {
  int i = blockIdx.x * 256 + threadIdx.x;
  if (i < NB2 * 2 * HW) {
    float e = edf[i];
    flow[i] += df[i] + e;
    eflow[i] += e;
  }
}

__global__ __launch_bounds__(256) void upsample_k(const float* __restrict__ flow,
                                                  const ushort_t* __restrict__ mask,
                                                  float* __restrict__ out) {
  const int j = threadIdx.x & 7;
  const int xh = threadIdx.x >> 3;
  const int x = blockIdx.x * 32 + xh;
  const int i = blockIdx.y;
  const int nz = blockIdx.z;
  const int nb = nz / 48, yy = nz - nb * 48;
  const int rem = yy * 64 + x;
  const ushort_t* mp = mask + ((size_t)nb * HW + rem) * 576;
  float m[9];
  float mx = -1e30f;
#pragma unroll
  for (int k = 0; k < 9; ++k) {
    m[k] = bf2f(mp[k * 64 + i * 8 + j]);
    mx = fmaxf(mx, m[k]);
  }
  float sum = 0.f;
#pragma unroll
  for (int k = 0; k < 9; ++k) {
    m[k] = __expf(m[k] - mx);
    sum += m[k];
  }
  const float inv = 8.f / sum;
#pragma unroll
  for (int ch = 0; ch < 2; ++ch) {
    float acc = 0.f;
#pragma unroll
    for (int k = 0; k < 9; ++k) {
      const int gy = yy + k / 3 - 1;
      const int gx = x + (k - (k / 3) * 3) - 1;
      float f = 0.f;
      if ((unsigned)gy < 48u && (unsigned)gx < 64u)
        f = flow[((size_t)(nb * 2 + ch)) * HW + gy * 64 + gx];
      acc = fmaf(m[k], f, acc);
    }
    out[(((size_t)(nb * 2 + ch)) * 384 + (yy * 8 + i)) * 512 + x * 8 + j] = acc * inv;
  }
}

// ---------------------------------------------------------------------------
// host orchestration
// ---------------------------------------------------------------------------
extern "C" void kernel_launch(void* const* d_in, const int* in_sizes, int n_in,
                              void* d_out, int out_size, void* d_ws, size_t ws_size,
                              hipStream_t stream) {
  (void)in_sizes; (void)n_in; (void)out_size;

  size_t off = 0;
  char* base = (char*)d_ws;
  auto take = [&](size_t nbytes) -> void* {
    void* p = base + off;
    off += (nbytes + 255) & ~(size_t)255;
    return p;
  };
  ushort_t* pyrA[4];
  ushort_t* pyrB[4];
  const int lsz[4] = {3072, 768, 192, 48};
  for (int l = 0; l < 4; ++l) pyrA[l] = (ushort_t*)take((size_t)NP * lsz[l] * 2);
  for (int l = 0; l < 4; ++l) pyrB[l] = (ushort_t*)take((size_t)NP * lsz[l] * 2);
  ushort_t* FMT[4];
  for (int s = 0; s < 4; ++s) FMT[s] = (ushort_t*)take((size_t)NP * 256 * 2);
  ushort_t* CORRb[2];
  CORRb[0] = (ushort_t*)take((size_t)NP * 384 * 2);
  CORRb[1] = (ushort_t*)take((size_t)NP * 384 * 2);
  ushort_t* NETb[2];
  NETb[0] = (ushort_t*)take((size_t)NP * 128 * 2);
  NETb[1] = (ushort_t*)take((size_t)NP * 128 * 2);
  ushort_t* NETBb[2];
  NETBb[0] = (ushort_t*)take((size_t)NP * 128 * 2);
  NETBb[1] = (ushort_t*)take((size_t)NP * 128 * 2);
  ushort_t* Xb[2];
  Xb[0] = (ushort_t*)take((size_t)NP * 256 * 2);
  Xb[1] = (ushort_t*)take((size_t)NP * 256 * 2);
  ushort_t* ACT1b[2];
  ACT1b[0] = (ushort_t*)take((size_t)NP * 256 * 2);
  ACT1b[1] = (ushort_t*)take((size_t)NP * 256 * 2);
  ushort_t* CFBb[2];
  CFBb[0] = (ushort_t*)take((size_t)NP * 256 * 2);
  CFBb[1] = (ushort_t*)take((size_t)NP * 256 * 2);
  ushort_t* FLOb[2];
  FLOb[0] = (ushort_t*)take((size_t)NP * 128 * 2);
  FLOb[1] = (ushort_t*)take((size_t)NP * 128 * 2);
  ushort_t* ZRBb[2];
  ZRBb[0] = (ushort_t*)take((size_t)NP * 256 * 2);
  ZRBb[1] = (ushort_t*)take((size_t)NP * 256 * 2);
  ushort_t* A512b[2];
  A512b[0] = (ushort_t*)take((size_t)NP * 512 * 2);
  A512b[1] = (ushort_t*)take((size_t)NP * 512 * 2);
  ushort_t* MASKB = (ushort_t*)take((size_t)NP * 576 * 2);
  float* FLOW = (float*)take((size_t)NB2 * 2 * HW * 4);
  float* EFLOW = (float*)take((size_t)NB2 * 2 * HW * 4);
  float* DF = (float*)take((size_t)NB2 * 2 * HW * 4);
  float* EDF = (float*)take((size_t)NB2 * 2 * HW * 4);

  static const int WSZ[15] = {82944, 442368, 12544, 73728, 290304,
                              245760, 245760, 245760, 245760, 245760, 245760,
                              294912, 4608, 294912, 147456};
  static const int BSZ[15] = {256, 192, 128, 64, 126, 128, 128, 128,
                              128, 128, 128, 256, 2, 256, 576};
  float* Wf[15];
  float* Bf[15];
  for (int s = 0; s < 5; ++s) Wf[s] = (float*)take((size_t)WSZ[s] * 4);
  Wf[5] = (float*)take((size_t)2 * 245760 * 4); Wf[6] = Wf[5] + 245760;
  Wf[7] = (float*)take((size_t)245760 * 4);
  Wf[8] = (float*)take((size_t)2 * 245760 * 4); Wf[9] = Wf[8] + 245760;
  Wf[10] = (float*)take((size_t)245760 * 4);
  Wf[11] = (float*)take((size_t)2 * 294912 * 4); Wf[13] = Wf[11] + 294912;
  Wf[12] = (float*)take((size_t)4608 * 4);
  Wf[14] = (float*)take((size_t)147456 * 4);
  for (int s = 0; s < 5; ++s) Bf[s] = (float*)take((size_t)BSZ[s] * 4);
  Bf[5] = (float*)take((size_t)2 * 128 * 4); Bf[6] = Bf[5] + 128;
  Bf[7] = (float*)take((size_t)128 * 4);
  Bf[8] = (float*)take((size_t)2 * 128 * 4); Bf[9] = Bf[8] + 128;
  Bf[10] = (float*)take((size_t)128 * 4);
  Bf[11] = (float*)take((size_t)2 * 256 * 4); Bf[13] = Bf[11] + 256;
  Bf[12] = (float*)take((size_t)2 * 4);
  Bf[14] = (float*)take((size_t)576 * 4);
  ushort_t* PBmc1 = (ushort_t*)take((size_t)16 * 12 * 512 * 2);
  ushort_t* PBmc2 = (ushort_t*)take((size_t)16 * 72 * 512 * 2);
  ushort_t* PBmf2 = (ushort_t*)take((size_t)8 * 36 * 512 * 2);
  ushort_t* PBmo = (ushort_t*)take((size_t)8 * 72 * 512 * 2);
  ushort_t* PBgzr1 = (ushort_t*)take((size_t)16 * 60 * 512 * 2);
  ushort_t* PBgq1 = (ushort_t*)take((size_t)8 * 60 * 512 * 2);
  ushort_t* PBgzr2 = (ushort_t*)take((size_t)16 * 60 * 512 * 2);
  ushort_t* PBgq2 = (ushort_t*)take((size_t)8 * 60 * 512 * 2);
  ushort_t* PBfh = (ushort_t*)take((size_t)32 * 36 * 512 * 2);
  ushort_t* PBmk2 = (ushort_t*)take((size_t)40 * 8 * 512 * 2);
  ushort_t* PBfh2 = (ushort_t*)take((size_t)1 * 72 * 512 * 2);
  int* FLAG = (int*)take(256);

  if (off > ws_size) return;

  detect_k<<<1, 256, 0, stream>>>((const ushort_t*)d_in[0], FLAG);
  CvtArgs ca;
  for (int s = 0; s < 15; ++s) {
    ca.src[s] = d_in[6 + 2 * s];
    ca.dst[s] = Wf[s];
    ca.n[s] = WSZ[s];
    ca.src[15 + s] = d_in[7 + 2 * s];
    ca.dst[15 + s] = Bf[s];
    ca.n[15 + s] = BSZ[s];
  }
  cvt_all_k<<<512, 256, 0, stream>>>(ca, FLAG);

  trans_k<<<dim3((NP * 256 + 255) / 256, 4), 256, 0, stream>>>(
      d_in[0], d_in[1], d_in[2], d_in[3], FMT[0], FMT[1], FMT[2], FMT[3], FLAG);
  init2_k<<<dim3((NB2 * 128 * HW + 255) / 256, 2), 256, 0, stream>>>(
      d_in[4], d_in[5], NETb[0], NETb[1], Xb[0], Xb[1], FLAG);

  auto pack = [&](const float* src, ushort_t* dst, int CO, int NB16, int CI, int KHKW, int NCH) {
    int total = NB16 * NCH * KHKW * 2 * 512;
    pack_k<<<(total + 255) / 256, 256, 0, stream>>>(src, dst, CO, CI, KHKW, NCH, total);
  };
  pack(Wf[0], PBmc1, 256, 16, 324, 1, 6);
  pack(Wf[1], PBmc2, 192, 16, 256, 9, 4);
  pack(Wf[3], PBmf2, 64, 8, 128, 9, 2);
  pack(Wf[4], PBmo, 126, 8, 256, 9, 4);
  pack(Wf[5], PBgzr1, 256, 16, 384, 5, 6);
  pack(Wf[7], PBgq1, 128, 8, 384, 5, 6);
  pack(Wf[8], PBgzr2, 256, 16, 384, 5, 6);
  pack(Wf[10], PBgq2, 128, 8, 384, 5, 6);
  pack(Wf[11], PBfh, 512, 32, 128, 9, 2);
  pack(Wf[14], PBmk2, 576, 40, 256, 1, 4);
  pack(Wf[12], PBfh2, 2, 1, 256, 9, 4);

  {
    CorrPtrs cp;
    for (int s = 0; s < 4; ++s) cp.f[s] = FMT[s];
    cp.out[0] = pyrA[0];
    cp.out[1] = pyrB[0];
    corr_mfma_k<<<dim3(96, 24, 4), 256, 0, stream>>>(cp);
  }
  {
    const int wsv[4] = {64, 32, 16, 8};
    const int hsv[4] = {48, 24, 12, 6};
    for (int l = 0; l < 3; ++l) {
      int ho = hsv[l + 1], wo = wsv[l + 1];
      int total = NP * ho * wo;
      avgpool_k<<<dim3((total + 255) / 256, 2), 256, 0, stream>>>(
          pyrA[l], pyrB[l], pyrA[l + 1], pyrB[l + 1], wsv[l], ho, wo, total);
    }
  }
  (void)hipMemsetAsync(FLOW, 0, (size_t)NB2 * 2 * HW * 4, stream);
  (void)hipMemsetAsync(EFLOW, 0, (size_t)NB2 * 2 * HW * 4, stream);

  float* outp = (float*)d_out;

  LkPtrs lk;
  lk.a0 = pyrA[0]; lk.a1 = pyrA[1]; lk.a2 = pyrA[2]; lk.a3 = pyrA[3];
  lk.b0 = pyrB[0]; lk.b1 = pyrB[1]; lk.b2 = pyrB[2]; lk.b3 = pyrB[3];
  lk.flow[0] = FLOW; lk.flow[1] = EFLOW;
  lk.out[0] = CORRb[0]; lk.out[1] = CORRb[1];

  auto BP = [&](const ushort_t* a0, const ushort_t* a1, const ushort_t* b0,
                const ushort_t* b1, const ushort_t* z0, const ushort_t* z1,
                const ushort_t* o0, const ushort_t* o1, void* y0, void* y1) {
    BrPtrs p;
    p.xa[0] = a0; p.xa[1] = a1; p.xb[0] = b0; p.xb[1] = b1;
    p.zr[0] = z0; p.zr[1] = z1; p.old_[0] = o0; p.old_[1] = o1;
    p.y[0] = y0; p.y[1] = y1;
    return p;
  };
  const ushort_t* NU = nullptr;

  for (int it = 0; it < ITERS; ++it) {
    lookup_k<<<dim3(6144, 2), 384, 0, stream>>>(lk);
    // motion encoder
    conv_mfma_k<1, 1, 0, 0, 1, 0, false, false, 4><<<dim3(48, 2, 4), 256, 0, stream>>>(
        BP(CORRb[0], CORRb[1], NU, NU, NU, NU, NU, NU, ACT1b[0], ACT1b[1]),
        PBmc1, Bf[0], 6, 384, 0, 0, 256, 256, 1.f, 2, 2);
    conv_mfma_k<3, 3, 1, 1, 1, 0, false, false, 4><<<dim3(48, 2, 4), 256, 0, stream>>>(
        BP(ACT1b[0], ACT1b[1], NU, NU, NU, NU, NU, NU, CFBb[0], CFBb[1]),
        PBmc2, Bf[1], 4, 256, 0, 0, 256, 256, 1.f, 2, 2);
    mf1_k<<<dim3(48, 4), 256, 0, stream>>>(FLOW, EFLOW, Wf[2], Bf[2],
                                           FLOb[0], FLOb[1], Xb[0], Xb[1]);
    conv_mfma_k<3, 3, 1, 1, 1, 0, false, false, 2><<<dim3(48, 2, 4), 256, 0, stream>>>(
        BP(FLOb[0], FLOb[1], NU, NU, NU, NU, NU, NU, CFBb[0], CFBb[1]),
        PBmf2, Bf[3], 2, 128, 0, 192, 256, 256, 1.f, 2, 2);
    conv_mfma_k<3, 3, 1, 1, 1, 0, false, false, 2><<<dim3(48, 2, 4), 256, 0, stream>>>(
        BP(CFBb[0], CFBb[1], NU, NU, NU, NU, NU, NU, Xb[0], Xb[1]),
        PBmo, Bf[4], 4, 256, 0, 128, 256, 254, 1.f, 2, 2);
    // GRU horizontal (1x5)
    conv_mfma_k<1, 5, 0, 2, 2, 1, false, false, 4><<<dim3(48, 2, 4), 256, 0, stream>>>(
        BP(NETb[0], NETb[1], Xb[0], Xb[1], NU, NU, NU, NU, ZRBb[0], ZRBb[1]),
        PBgzr1, Bf[5], 6, 0, 0, 0, 256, 256, 1.f, 2, 2);
    conv_mfma_k<1, 5, 0, 2, 3, 2, true, false, 2><<<dim3(48, 2, 4), 256, 0, stream>>>(
        BP(NETb[0], NETb[1], Xb[0], Xb[1], ZRBb[0], ZRBb[1], NETb[0], NETb[1],
           NETBb[0], NETBb[1]),
        PBgq1, Bf[7], 6, 0, 0, 0, 128, 128, 1.f, 2, 2);
    // GRU vertical (5x1)
    conv_mfma_k<5, 1, 2, 0, 2, 1, false, false, 4><<<dim3(48, 2, 4), 256, 0, stream>>>(
        BP(NETBb[0], NETBb[1], Xb[0], Xb[1], NU, NU, NU, NU, ZRBb[0], ZRBb[1]),
        PBgzr2, Bf[8], 6, 0, 0, 0, 256, 256, 1.f, 2, 2);
    conv_mfma_k<5, 1, 2, 0, 3, 2, true, false, 2><<<dim3(48, 2, 4), 256, 0, stream>>>(
        BP(NETBb[0], NETBb[1], Xb[0], Xb[1], ZRBb[0], ZRBb[1], NETBb[0], NETBb[1],
           NETb[0], NETb[1]),
        PBgq2, Bf[10], 6, 0, 0, 0, 128, 128, 1.f, 2, 2);
    // heads
    conv_mfma_k<3, 3, 1, 1, 1, 0, false, false, 4><<<dim3(48, 4, 4), 256, 0, stream>>>(
        BP(NETb[0], NETb[1], NU, NU, NU, NU, NU, NU, A512b[0], A512b[1]),
        PBfh, Bf[11], 2, 128, 0, 0, 512, 512, 1.f, 2, 2);
    conv_mfma_k<3, 3, 1, 1, 0, 0, false, true, 1><<<dim3(48, 1, 4), 256, 0, stream>>>(
        BP(A512b[0], A512b[1], NU, NU, NU, NU, NU, NU, DF, EDF),
        PBfh2, Bf[12], 4, 512, 0, 0, 2, 2, 1.f, 2, 1);
    conv_mfma_k<1, 1, 0, 0, 0, 0, false, false, 4><<<dim3(48, 5, 2), 256, 0, stream>>>(
        BP(A512b[0], NU, NU, NU, NU, NU, NU, NU, (void*)MASKB, nullptr),
        PBmk2, Bf[14], 4, 512, 256, 0, 576, 576, 0.25f, 1, 99);
    flow_update_k<<<48, 256, 0, stream>>>(FLOW, EFLOW, DF, EDF);
    upsample_k<<<dim3(2, 8, 96), 256, 0, stream>>>(FLOW, MASKB,
                                                   outp + (size_t)it * (NB2 * 2 * 384 * 512));
  }
}